// Round 1
// baseline (352.347 us; speedup 1.0000x reference)
//
#include <hip/hip_runtime.h>
#include <hip/hip_bf16.h>

// Problem constants (match reference)
#define HH 1024
#define WW 1024
#define NN (HH * WW)
#define KK 15
#define GAMMA_F 0.5f

// One thread per pixel n. For each of K=15 neighbors:
//   plane = s2[0,n]*dist[k,0,n] + s2[1,n]*dist[k,1,n]
//   a1    = (s1[n] - s1[j] - plane) * w[k,n]        -> acc1 += a1^2
//   e     = s2[:,n] - s2[:,j]                        -> acc2 += |e| * w[k,n]
// per-pixel contribution = sqrt(acc1) + GAMMA*acc2; reduce; *(1/N) at the end.
__global__ __launch_bounds__(256) void ppr_kernel(
    const float* __restrict__ s1,      // (N,)
    const float* __restrict__ s2,      // (2, N)
    const float* __restrict__ w,       // (K, N)
    const float* __restrict__ dist,    // (K, 2, N)
    const int* __restrict__ nb,        // (K, N)
    float* __restrict__ out)           // scalar
{
    const int n = blockIdx.x * blockDim.x + threadIdx.x;

    float local = 0.0f;
    if (n < NN) {
        const float s1n = s1[n];
        const float s2a = s2[n];
        const float s2b = s2[NN + n];

        float acc1 = 0.0f;  // sum_k (a1*w)^2
        float acc2 = 0.0f;  // sum_k |e|*w

#pragma unroll
        for (int k = 0; k < KK; ++k) {
            const int   j  = nb[k * NN + n];
            const float wk = w[k * NN + n];
            const float d0 = dist[(2 * k + 0) * NN + n];
            const float d1 = dist[(2 * k + 1) * NN + n];

            const float plane = fmaf(s2a, d0, s2b * d1);
            const float a1 = (s1n - s1[j] - plane) * wk;
            acc1 = fmaf(a1, a1, acc1);

            const float e0 = s2a - s2[j];
            const float e1 = s2b - s2[NN + j];
            acc2 = fmaf(sqrtf(fmaf(e0, e0, e1 * e1)), wk, acc2);
        }
        local = sqrtf(acc1) + GAMMA_F * acc2;
    }

    // Wave-level reduction (wave = 64 lanes on CDNA)
#pragma unroll
    for (int off = 32; off > 0; off >>= 1)
        local += __shfl_down(local, off, 64);

    __shared__ float smem[4];  // 256 threads / 64 lanes = 4 waves
    const int wave = threadIdx.x >> 6;
    const int lane = threadIdx.x & 63;
    if (lane == 0) smem[wave] = local;
    __syncthreads();

    if (threadIdx.x == 0) {
        const float s = smem[0] + smem[1] + smem[2] + smem[3];
        // MULTIPLIER == 1.0; fold the 1/N here.
        atomicAdd(out, s * (1.0f / (float)NN));
    }
}

extern "C" void kernel_launch(void* const* d_in, const int* in_sizes, int n_in,
                              void* d_out, int out_size, void* d_ws, size_t ws_size,
                              hipStream_t stream) {
    const float* s1   = (const float*)d_in[0];  // sig1 (1,1,H,W)
    const float* s2   = (const float*)d_in[1];  // sig2 (1,2,H,W)
    const float* w    = (const float*)d_in[2];  // weights (K,N)
    const float* dist = (const float*)d_in[3];  // dist (K,2,N)
    const int*   nb   = (const int*)d_in[4];    // neighbours (K,N)
    float* out = (float*)d_out;

    // d_out is re-poisoned to 0xAA before every timed launch; zero it first.
    hipMemsetAsync(out, 0, sizeof(float) * (size_t)out_size, stream);

    const int block = 256;
    const int grid  = (NN + block - 1) / block;  // 4096 blocks
    ppr_kernel<<<grid, block, 0, stream>>>(s1, s2, w, dist, nb, out);
}